// Round 10
// baseline (173.802 us; speedup 1.0000x reference)
//
#include <hip/hip_runtime.h>
#include <math.h>
#include <cstdint>
#include <cstddef>

typedef unsigned short u16;
typedef short bf16x8 __attribute__((ext_vector_type(8)));
typedef float f32x4 __attribute__((ext_vector_type(4)));
typedef u16 u16x8 __attribute__((ext_vector_type(8)));
typedef u16 u16x4 __attribute__((ext_vector_type(4)));

#define T_LEN 4096
#define NH 12
#define HD 64
#define DMODEL 768
#define GK 768                    // K dim for both GEMMs
#define QKV_STRIDE 6291456ul      // elems per q/k/v tensor = 8192*768

__device__ __forceinline__ u16 f2bf(float x) {
  union { float f; unsigned u; } v; v.f = x;
  unsigned r = v.u + 0x7fffu + ((v.u >> 16) & 1u);
  return (u16)(r >> 16);
}

__device__ __forceinline__ void async16(const u16* g, u16* l) {
  __builtin_amdgcn_global_load_lds(
      (const __attribute__((address_space(1))) unsigned int*)g,
      (__attribute__((address_space(3))) unsigned int*)l, 16, 0, 0);
}

// ---------------- fused fp32 -> bf16 conversion (x + 4 weights, one launch) ----------------
__global__ void cvt_all(const float* __restrict__ x,
                        const float* __restrict__ Wq, const float* __restrict__ Wk,
                        const float* __restrict__ Wv, const float* __restrict__ Wo,
                        u16* __restrict__ xb, u16* __restrict__ wqkv, u16* __restrict__ wo_b) {
  int bx = blockIdx.x;
  const float* s; u16* d; int base;
  if (bx < 6144)      { s = x;  d = xb;             base = bx; }
  else if (bx < 6720) { s = Wq; d = wqkv;           base = bx - 6144; }
  else if (bx < 7296) { s = Wk; d = wqkv + 589824;  base = bx - 6720; }
  else if (bx < 7872) { s = Wv; d = wqkv + 1179648; base = bx - 7296; }
  else                { s = Wo; d = wo_b;           base = bx - 7872; }
  int i = (base * 256 + (int)threadIdx.x) * 4;
  float4 v = *(const float4*)(s + i);
  u16x4 o;
  o[0] = f2bf(v.x); o[1] = f2bf(v.y); o[2] = f2bf(v.z); o[3] = f2bf(v.w);
  *(u16x4*)(d + i) = o;
}

// ---------------- GEMM: C = A[M,K] * B[N,K]^T + bias ----------------
// Tile BMt x 128 (BMt = MI*32), BK=64, 256 threads (4 waves 2x2), 16x16x32 bf16 MFMA.
// global_load_lds staging; 12 K-iters (barrier drains halved vs BK=32).
// XOR swizzle: LDS[row][c'] = global chunk c'^(row&7); staging lane l covers
// row base+(l>>3), global chunk (l&7)^((l>>3)&7) (coalesced 128B rows, LDS
// dest lane-linear); frag read chunk (kh+4*h2)^(r16&7) -> balanced banks.
// EPI=0: Q/K bf16 row-major [8192,768] x2 tensors (bias0/bias1 select by bn0)
// EPI=1: fp32 direct store [8192,768] (+bias0)
// EPI=2: V bf16 block-transposed [b*12+h][t>>4][d][t&15], coalesced u16x4 stores
#define BN 128
#define BK 64

template <int EPI, int MI>
__global__ __launch_bounds__(256)
void gemm_bt(const u16* __restrict__ A, const u16* __restrict__ B,
             const float* __restrict__ bias0, const float* __restrict__ bias1,
             void* __restrict__ outp) {
  constexpr int BMt = MI * 32;
  __shared__ __align__(16) u16 As[BMt * BK];
  __shared__ __align__(16) u16 Bs[BN * BK];

  const int tid  = threadIdx.x;
  const int lane = tid & 63;
  const int wave = tid >> 6;
  const int wm = wave & 1, wn = wave >> 1;
  const long am0 = (long)blockIdx.x * BMt;
  const long bn0 = (long)blockIdx.y * BN;
  const int r16 = lane & 15;
  const int kh  = lane >> 4;
  const int swr = (r16 & 7);   // row-based swizzle for frag reads

  f32x4 acc[MI][4] = {};

  // staging: lane l -> row (l>>3), chunk (l&7)^((l>>3)&7); base rows multiple of 8
  const int lrow = lane >> 3;
  const int lch  = ((lane & 7) ^ (lrow & 7)) * 8;
  const u16* Ag = A + (am0 + lrow) * GK + lch;
  const u16* Bg = B + (bn0 + lrow) * GK + lch;

  for (int kt = 0; kt < GK; kt += BK) {
    __syncthreads();
    // A: BMt rows, 8 rows per async16; wave issues MI instrs at rows wave*8*MI + s*8
#pragma unroll
    for (int s = 0; s < MI; s++) {
      int br = wave * 8 * MI + s * 8;
      async16(Ag + (size_t)br * GK + kt, &As[br * BK]);
    }
    // B: 128 rows, 4 instrs per wave
#pragma unroll
    for (int s = 0; s < 4; s++) {
      int br = wave * 32 + s * 8;
      async16(Bg + (size_t)br * GK + kt, &Bs[br * BK]);
    }
    __syncthreads();
#pragma unroll
    for (int h2 = 0; h2 < 2; h2++) {
      const int sw8 = ((kh + 4 * h2) ^ swr) * 8;
      bf16x8 af[MI], bfr[4];
#pragma unroll
      for (int i = 0; i < MI; i++)
        af[i] = *(const bf16x8*)&As[(wm * MI * 16 + i * 16 + r16) * BK + sw8];
#pragma unroll
      for (int j = 0; j < 4; j++)
        bfr[j] = *(const bf16x8*)&Bs[(wn * 64 + j * 16 + r16) * BK + sw8];
#pragma unroll
      for (int i = 0; i < MI; i++)
#pragma unroll
        for (int j = 0; j < 4; j++)
          acc[i][j] = __builtin_amdgcn_mfma_f32_16x16x32_bf16(af[i], bfr[j], acc[i][j], 0, 0, 0);
    }
  }

  const int m0 = (int)am0 + wm * MI * 16;   // global row base of this wave's subtile

  if (EPI == 0) {
    // Q or K: row-major [8192][768], tensor selected by bn0
    const int tens = (int)(bn0 >= 768);
    const int c0 = (int)bn0 - tens * 768;
    const float* bp = tens ? bias1 : bias0;
    u16* outb = (u16*)outp + (size_t)tens * QKV_STRIDE;
#pragma unroll
    for (int j = 0; j < 4; j++) {
      int col = c0 + wn * 64 + j * 16 + r16;
      float bv = bp[col];
#pragma unroll
      for (int i = 0; i < MI; i++) {
#pragma unroll
        for (int r = 0; r < 4; r++) {
          int row = m0 + i * 16 + kh * 4 + r;
          outb[(size_t)row * DMODEL + col] = f2bf(acc[i][j][r] + bv);
        }
      }
    }
  } else if (EPI == 2) {
    // V: block-transposed [b*12+h][t>>4][d][t&15]
    u16* vtb = (u16*)outp;
    const int kr = kh * 4;
#pragma unroll
    for (int j = 0; j < 4; j++) {
      int cl = (int)bn0 + wn * 64 + j * 16;   // multiple of 16, lane-uniform
      int hj = cl >> 6;
      int dlane = (cl & 63) + r16;
      float bv = bias0[cl + r16];
#pragma unroll
      for (int i = 0; i < MI; i++) {
        int row0 = m0 + i * 16;
        int b_ = row0 >> 12;
        int tb = (row0 & 4095) >> 4;
        size_t base = (((size_t)(b_ * NH + hj) * 256 + tb) << 10) + dlane * 16 + kr;
        u16x4 pk;
#pragma unroll
        for (int r = 0; r < 4; r++) pk[r] = f2bf(acc[i][j][r] + bv);
        *(u16x4*)(vtb + base) = pk;
      }
    }
  } else {
    float* O = (float*)outp;
#pragma unroll
    for (int i = 0; i < MI; i++) {
#pragma unroll
      for (int r = 0; r < 4; r++) {
        int row = m0 + i * 16 + kh * 4 + r;
        float* orow = O + (size_t)row * DMODEL;
#pragma unroll
        for (int j = 0; j < 4; j++) {
          int col = (int)bn0 + wn * 64 + j * 16 + r16;
          orow[col] = acc[i][j][r] + bias0[col];
        }
      }
    }
  }
}

// ---------------- MFMA banded local attention ----------------
// 64 queries/block (4 waves x 16 queries). Q,K row-major [8192][768];
// V block-transposed [bh][tb][d][tl]. Per wave: 6 MFMA scores (16x48),
// masked softmax (intra-quad shfl reductions), P -> LDS (C-layout -> A-layout),
// 8 MFMA PV with V B-frags read directly from global. O staged through the
// wave-private Ps buffer for coalesced 128B-row stores. Out bf16 [8192][768].
#define PSS 72   // Ps row stride (u16): 144B, 16B-aligned, 2-way banks (free)

__global__ __launch_bounds__(256)
void attn_mfma(const u16* __restrict__ qkv, const u16* __restrict__ vt,
               u16* __restrict__ attn) {
  __shared__ __align__(16) u16 Ps[4][16 * PSS];   // 9216 B
  const int tid = threadIdx.x, lane = tid & 63, wave = tid >> 6;
  const int r16 = lane & 15, quad = lane >> 4;
  const int q0 = blockIdx.x * 64;
  const int h = blockIdx.y, b = blockIdx.z;
  const long rowbase = (long)b * T_LEN;
  const int hc = h * HD;
  const u16* Qg = qkv;
  const u16* Kg = qkv + QKV_STRIDE;
  const u16* Vh = vt + ((size_t)(b * NH + h)) * (256 * 1024);

  const int qbase = q0 + wave * 16;   // first query of this wave
  const int kb = qbase - 16;          // first key (mult of 16, may be <0)

  // Q A-frags: rows qbase+r16, dims quad*8 (+0 / +32)
  const u16* qrow = Qg + (rowbase + qbase + r16) * DMODEL + hc + quad * 8;
  bf16x8 qa0 = *(const bf16x8*)qrow;
  bf16x8 qa1 = *(const bf16x8*)(qrow + 32);

  // scores: 3 key tiles x (K=64 -> 2 mfma)
  f32x4 s[3];
#pragma unroll
  for (int t = 0; t < 3; t++) {
    const u16* krow = Kg + (rowbase + kb + t * 16 + r16) * DMODEL + hc + quad * 8;
    bf16x8 kf0 = *(const bf16x8*)krow;
    bf16x8 kf1 = *(const bf16x8*)(krow + 32);
    f32x4 a = {};
    a = __builtin_amdgcn_mfma_f32_16x16x32_bf16(qa0, kf0, a, 0, 0, 0);
    a = __builtin_amdgcn_mfma_f32_16x16x32_bf16(qa1, kf1, a, 0, 0, 0);
    s[t] = a;
  }

  // masked softmax per C-row (query = qbase + quad*4 + r), cols across quad lanes
  float pr[3][4];
#pragma unroll
  for (int r = 0; r < 4; r++) {
    const int qg = qbase + quad * 4 + r;
    float sc[3];
#pragma unroll
    for (int t = 0; t < 3; t++) {
      int key = kb + t * 16 + r16;
      bool ok = (key >= qg - 16) && (key <= qg + 16) && (key >= 0) && (key < T_LEN);
      sc[t] = ok ? s[t][r] * 0.125f : -INFINITY;
    }
    float mx = fmaxf(sc[0], fmaxf(sc[1], sc[2]));
    mx = fmaxf(mx, __shfl_xor(mx, 1));
    mx = fmaxf(mx, __shfl_xor(mx, 2));
    mx = fmaxf(mx, __shfl_xor(mx, 4));
    mx = fmaxf(mx, __shfl_xor(mx, 8));
    float e0 = __expf(sc[0] - mx), e1 = __expf(sc[1] - mx), e2 = __expf(sc[2] - mx);
    float l = e0 + e1 + e2;
    l += __shfl_xor(l, 1);
    l += __shfl_xor(l, 2);
    l += __shfl_xor(l, 4);
    l += __shfl_xor(l, 8);
    float inv = 1.0f / l;
    pr[0][r] = e0 * inv; pr[1][r] = e1 * inv; pr[2][r] = e2 * inv;
  }

  // P: C-layout -> LDS (rows=query, cols=key rel kb), zero pad cols 48..63
  u16* psw = &Ps[wave][0];
#pragma unroll
  for (int t = 0; t < 3; t++)
#pragma unroll
    for (int r = 0; r < 4; r++)
      psw[(quad * 4 + r) * PSS + t * 16 + r16] = f2bf(pr[t][r]);
#pragma unroll
  for (int r = 0; r < 4; r++)
    psw[(quad * 4 + r) * PSS + 48 + r16] = 0;

  // P A-frags (keys 0..31, 32..47+pad)
  bf16x8 pa0 = *(const bf16x8*)&psw[r16 * PSS + quad * 8];
  bf16x8 pa1 = *(const bf16x8*)&psw[r16 * PSS + 32 + quad * 8];

  // PV: 4 d-col tiles x 2 k-frags; V B-frags direct from transposed global
  const int kq1 = kb + quad * 8;
  const int kq2 = kb + 32 + quad * 8;
  const int o1 = (kq1 >> 4) * 1024 + (kq1 & 15);
  const int o2 = (kq2 >> 4) * 1024 + (kq2 & 15);
  f32x4 o[4];
#pragma unroll
  for (int c = 0; c < 4; c++) {
    const u16* vb = Vh + (16 * c + r16) * 16;
    bf16x8 v1 = *(const bf16x8*)(vb + o1);
    bf16x8 v2 = *(const bf16x8*)(vb + o2);
    f32x4 a = {};
    a = __builtin_amdgcn_mfma_f32_16x16x32_bf16(pa0, v1, a, 0, 0, 0);
    a = __builtin_amdgcn_mfma_f32_16x16x32_bf16(pa1, v2, a, 0, 0, 0);
    o[c] = a;
  }

  // O: stage through Ps (wave-private, P-frags already consumed), then
  // coalesced row stores: lane l handles rows l>>3 and 8+(l>>3), 16B each.
#pragma unroll
  for (int c = 0; c < 4; c++)
#pragma unroll
    for (int r = 0; r < 4; r++)
      psw[(quad * 4 + r) * PSS + 16 * c + r16] = f2bf(o[c][r]);
  {
    int rr = lane >> 3, cc = (lane & 7) * 8;
    u16x8 v0 = *(const u16x8*)&psw[rr * PSS + cc];
    u16x8 v1 = *(const u16x8*)&psw[(8 + rr) * PSS + cc];
    u16* ob = attn + (rowbase + qbase) * DMODEL + hc;
    *(u16x8*)(ob + (size_t)rr * DMODEL + cc) = v0;
    *(u16x8*)(ob + (size_t)(8 + rr) * DMODEL + cc) = v1;
  }
}

// ---------------- launch ----------------
extern "C" void kernel_launch(void* const* d_in, const int* in_sizes, int n_in,
                              void* d_out, int out_size, void* d_ws, size_t ws_size,
                              hipStream_t stream) {
  const float* x  = (const float*)d_in[0];
  const float* Wq = (const float*)d_in[1];
  const float* bq = (const float*)d_in[2];
  const float* Wk = (const float*)d_in[3];
  const float* bk = (const float*)d_in[4];
  const float* Wv = (const float*)d_in[5];
  const float* bv = (const float*)d_in[6];
  const float* Wo = (const float*)d_in[7];
  const float* bo = (const float*)d_in[8];
  float* out = (float*)d_out;
  char* ws = (char*)d_ws;

  u16* xb   = (u16*)(ws);                 // 8192*768 bf16
  u16* wqkv = (u16*)(ws + 12582912);      // 2304*768 bf16 (Wq,Wk,Wv rows)
  u16* wo_b = (u16*)(ws + 16121856);      // 768*768 bf16
  u16* qkv  = (u16*)(ws + 17301504);      // 3*6291456 bf16 (Q,K row-major; V transposed)
  u16* attnb = (u16*)(ws + 55050240);     // 8192*768 bf16

  cvt_all<<<8448, 256, 0, stream>>>(x, Wq, Wk, Wv, Wo, xb, wqkv, wo_b);

  // Q,K projection (row-major epilogue)
  gemm_bt<0, 4><<<dim3(64, 12), 256, 0, stream>>>(xb, wqkv, bq, bk, (void*)qkv);
  // V projection (block-transposed epilogue)
  gemm_bt<2, 4><<<dim3(64, 6), 256, 0, stream>>>(xb, wqkv + 1179648, bv, bv,
                                                 (void*)(qkv + 2 * QKV_STRIDE));
  attn_mfma<<<dim3(64, 12, 2), 256, 0, stream>>>(qkv, qkv + 2 * QKV_STRIDE, attnb);
  gemm_bt<1, 2><<<dim3(128, 6), 256, 0, stream>>>(attnb, wo_b, bo, bo, (void*)out);
}

// Round 11
// 168.496 us; speedup vs baseline: 1.0315x; 1.0315x over previous
//
#include <hip/hip_runtime.h>
#include <math.h>
#include <cstdint>
#include <cstddef>

typedef unsigned short u16;
typedef short bf16x8 __attribute__((ext_vector_type(8)));
typedef float f32x4 __attribute__((ext_vector_type(4)));
typedef u16 u16x8 __attribute__((ext_vector_type(8)));
typedef u16 u16x4 __attribute__((ext_vector_type(4)));

#define T_LEN 4096
#define NH 12
#define HD 64
#define DMODEL 768
#define GK 768                    // K dim for both GEMMs
#define QKV_STRIDE 6291456ul      // elems per q/k/v tensor = 8192*768

__device__ __forceinline__ u16 f2bf(float x) {
  union { float f; unsigned u; } v; v.f = x;
  unsigned r = v.u + 0x7fffu + ((v.u >> 16) & 1u);
  return (u16)(r >> 16);
}

__device__ __forceinline__ void async16(const u16* g, u16* l) {
  __builtin_amdgcn_global_load_lds(
      (const __attribute__((address_space(1))) unsigned int*)g,
      (__attribute__((address_space(3))) unsigned int*)l, 16, 0, 0);
}

// ---------------- fused fp32 -> bf16 conversion (x + 4 weights, one launch) ----------------
__global__ void cvt_all(const float* __restrict__ x,
                        const float* __restrict__ Wq, const float* __restrict__ Wk,
                        const float* __restrict__ Wv, const float* __restrict__ Wo,
                        u16* __restrict__ xb, u16* __restrict__ wqkv, u16* __restrict__ wo_b) {
  int bx = blockIdx.x;
  const float* s; u16* d; int base;
  if (bx < 6144)      { s = x;  d = xb;             base = bx; }
  else if (bx < 6720) { s = Wq; d = wqkv;           base = bx - 6144; }
  else if (bx < 7296) { s = Wk; d = wqkv + 589824;  base = bx - 6720; }
  else if (bx < 7872) { s = Wv; d = wqkv + 1179648; base = bx - 7296; }
  else                { s = Wo; d = wo_b;           base = bx - 7872; }
  int i = (base * 256 + (int)threadIdx.x) * 4;
  float4 v = *(const float4*)(s + i);
  u16x4 o;
  o[0] = f2bf(v.x); o[1] = f2bf(v.y); o[2] = f2bf(v.z); o[3] = f2bf(v.w);
  *(u16x4*)(d + i) = o;
}

// ---------------- GEMM: C = A[M,K] * B[N,K]^T + bias ----------------
// R8 structure (best measured): BK=32, async16 staging, XOR chunk swizzle
// LDS[row][c'] = global chunk c'^((row>>1)&3) -> conflict-free frag reads.
// 1-D grid with XCD swizzle: xcd = bid&7 owns x-range [xcd*NX/8, ...), so each
// XCD's A-slice (~1.6 MB) stays L2-resident across its y-tiles.
// EPI=0: Q/K bf16 row-major [8192,768] x2 tensors (bias0/bias1 select by bn0)
// EPI=1: fp32 direct store [8192,768] (+bias0)
// EPI=2: V bf16 block-transposed [b*12+h][t>>4][d][t&15], coalesced u16x4 stores
#define BN 128
#define BK 32

template <int EPI, int MI, int NX>
__global__ __launch_bounds__(256)
void gemm_bt(const u16* __restrict__ A, const u16* __restrict__ B,
             const float* __restrict__ bias0, const float* __restrict__ bias1,
             void* __restrict__ outp) {
  constexpr int BMt = MI * 32;
  constexpr int PER = NX / 8;     // x-tiles per XCD group
  __shared__ __align__(16) u16 As[BMt * BK];
  __shared__ __align__(16) u16 Bs[BN * BK];

  const int bid  = blockIdx.x;
  const int xcd  = bid & 7;
  const int slot = bid >> 3;
  const int bx   = xcd * PER + (slot % PER);
  const int by   = slot / PER;

  const int tid  = threadIdx.x;
  const int lane = tid & 63;
  const int wave = tid >> 6;
  const int wm = wave & 1, wn = wave >> 1;
  const long am0 = (long)bx * BMt;
  const long bn0 = (long)by * BN;
  const int r16 = lane & 15;
  const int kh  = lane >> 4;
  const int sw8 = (kh ^ ((r16 >> 1) & 3)) * 8;   // swizzled chunk offset for frag reads

  f32x4 acc[MI][4] = {};

  // staging: lane l -> row l>>2, global chunk (l&3)^((l>>3)&3); LDS dest lane-linear
  const int srow   = lane >> 2;
  const int schunk = ((lane & 3) ^ ((lane >> 3) & 3)) * 8;
  const u16* Ag = A + (am0 + wave * 16 + srow) * GK + schunk;
  const u16* Bg = B + (bn0 + wave * 16 + srow) * GK + schunk;
  u16* Bl0 = &Bs[(wave * 16) * BK];
  u16* Bl1 = &Bs[(64 + wave * 16) * BK];

  for (int kt = 0; kt < GK; kt += BK) {
    __syncthreads();
#pragma unroll
    for (int s = 0; s < MI / 2; s++)
      async16(Ag + (size_t)(s * 64) * GK + kt, &As[(s * 64 + wave * 16) * BK]);
    async16(Bg + kt, Bl0);
    async16(Bg + 64 * GK + kt, Bl1);
    __syncthreads();
    bf16x8 af[MI], bfr[4];
#pragma unroll
    for (int i = 0; i < MI; i++)
      af[i] = *(const bf16x8*)&As[(wm * MI * 16 + i * 16 + r16) * BK + sw8];
#pragma unroll
    for (int j = 0; j < 4; j++)
      bfr[j] = *(const bf16x8*)&Bs[(wn * 64 + j * 16 + r16) * BK + sw8];
#pragma unroll
    for (int i = 0; i < MI; i++)
#pragma unroll
      for (int j = 0; j < 4; j++)
        acc[i][j] = __builtin_amdgcn_mfma_f32_16x16x32_bf16(af[i], bfr[j], acc[i][j], 0, 0, 0);
  }

  const int m0 = (int)am0 + wm * MI * 16;   // global row base of this wave's subtile

  if (EPI == 0) {
    // Q or K: row-major [8192][768], tensor selected by bn0
    const int tens = (int)(bn0 >= 768);
    const int c0 = (int)bn0 - tens * 768;
    const float* bp = tens ? bias1 : bias0;
    u16* outb = (u16*)outp + (size_t)tens * QKV_STRIDE;
#pragma unroll
    for (int j = 0; j < 4; j++) {
      int col = c0 + wn * 64 + j * 16 + r16;
      float bv = bp[col];
#pragma unroll
      for (int i = 0; i < MI; i++) {
#pragma unroll
        for (int r = 0; r < 4; r++) {
          int row = m0 + i * 16 + kh * 4 + r;
          outb[(size_t)row * DMODEL + col] = f2bf(acc[i][j][r] + bv);
        }
      }
    }
  } else if (EPI == 2) {
    // V: block-transposed [b*12+h][t>>4][d][t&15]
    u16* vtb = (u16*)outp;
    const int kr = kh * 4;
#pragma unroll
    for (int j = 0; j < 4; j++) {
      int cl = (int)bn0 + wn * 64 + j * 16;   // multiple of 16, lane-uniform
      int hj = cl >> 6;
      int dlane = (cl & 63) + r16;
      float bv = bias0[cl + r16];
#pragma unroll
      for (int i = 0; i < MI; i++) {
        int row0 = m0 + i * 16;
        int b_ = row0 >> 12;
        int tb = (row0 & 4095) >> 4;
        size_t base = (((size_t)(b_ * NH + hj) * 256 + tb) << 10) + dlane * 16 + kr;
        u16x4 pk;
#pragma unroll
        for (int r = 0; r < 4; r++) pk[r] = f2bf(acc[i][j][r] + bv);
        *(u16x4*)(vtb + base) = pk;
      }
    }
  } else {
    float* O = (float*)outp;
#pragma unroll
    for (int i = 0; i < MI; i++) {
#pragma unroll
      for (int r = 0; r < 4; r++) {
        int row = m0 + i * 16 + kh * 4 + r;
        float* orow = O + (size_t)row * DMODEL;
#pragma unroll
        for (int j = 0; j < 4; j++) {
          int col = (int)bn0 + wn * 64 + j * 16 + r16;
          orow[col] = acc[i][j][r] + bias0[col];
        }
      }
    }
  }
}

// ---------------- MFMA banded local attention ----------------
// 64 queries/block (4 waves x 16 queries). Q,K row-major [8192][768];
// V block-transposed [bh][tb][d][tl]. Per wave: 6 MFMA scores (16x48),
// masked softmax (intra-quad shfl reductions), P -> LDS (C-layout -> A-layout),
// 8 MFMA PV with V B-frags read directly from global. O staged through the
// wave-private Ps buffer for coalesced 128B-row stores. Out bf16 [8192][768].
#define PSS 72   // Ps row stride (u16): 144B, 16B-aligned, 2-way banks (free)

__global__ __launch_bounds__(256)
void attn_mfma(const u16* __restrict__ qkv, const u16* __restrict__ vt,
               u16* __restrict__ attn) {
  __shared__ __align__(16) u16 Ps[4][16 * PSS];   // 9216 B
  const int tid = threadIdx.x, lane = tid & 63, wave = tid >> 6;
  const int r16 = lane & 15, quad = lane >> 4;
  const int q0 = blockIdx.x * 64;
  const int h = blockIdx.y, b = blockIdx.z;
  const long rowbase = (long)b * T_LEN;
  const int hc = h * HD;
  const u16* Qg = qkv;
  const u16* Kg = qkv + QKV_STRIDE;
  const u16* Vh = vt + ((size_t)(b * NH + h)) * (256 * 1024);

  const int qbase = q0 + wave * 16;   // first query of this wave
  const int kb = qbase - 16;          // first key (mult of 16, may be <0)

  // Q A-frags: rows qbase+r16, dims quad*8 (+0 / +32)
  const u16* qrow = Qg + (rowbase + qbase + r16) * DMODEL + hc + quad * 8;
  bf16x8 qa0 = *(const bf16x8*)qrow;
  bf16x8 qa1 = *(const bf16x8*)(qrow + 32);

  // scores: 3 key tiles x (K=64 -> 2 mfma)
  f32x4 s[3];
#pragma unroll
  for (int t = 0; t < 3; t++) {
    const u16* krow = Kg + (rowbase + kb + t * 16 + r16) * DMODEL + hc + quad * 8;
    bf16x8 kf0 = *(const bf16x8*)krow;
    bf16x8 kf1 = *(const bf16x8*)(krow + 32);
    f32x4 a = {};
    a = __builtin_amdgcn_mfma_f32_16x16x32_bf16(qa0, kf0, a, 0, 0, 0);
    a = __builtin_amdgcn_mfma_f32_16x16x32_bf16(qa1, kf1, a, 0, 0, 0);
    s[t] = a;
  }

  // masked softmax per C-row (query = qbase + quad*4 + r), cols across quad lanes
  float pr[3][4];
#pragma unroll
  for (int r = 0; r < 4; r++) {
    const int qg = qbase + quad * 4 + r;
    float sc[3];
#pragma unroll
    for (int t = 0; t < 3; t++) {
      int key = kb + t * 16 + r16;
      bool ok = (key >= qg - 16) && (key <= qg + 16) && (key >= 0) && (key < T_LEN);
      sc[t] = ok ? s[t][r] * 0.125f : -INFINITY;
    }
    float mx = fmaxf(sc[0], fmaxf(sc[1], sc[2]));
    mx = fmaxf(mx, __shfl_xor(mx, 1));
    mx = fmaxf(mx, __shfl_xor(mx, 2));
    mx = fmaxf(mx, __shfl_xor(mx, 4));
    mx = fmaxf(mx, __shfl_xor(mx, 8));
    float e0 = __expf(sc[0] - mx), e1 = __expf(sc[1] - mx), e2 = __expf(sc[2] - mx);
    float l = e0 + e1 + e2;
    l += __shfl_xor(l, 1);
    l += __shfl_xor(l, 2);
    l += __shfl_xor(l, 4);
    l += __shfl_xor(l, 8);
    float inv = 1.0f / l;
    pr[0][r] = e0 * inv; pr[1][r] = e1 * inv; pr[2][r] = e2 * inv;
  }

  // P: C-layout -> LDS (rows=query, cols=key rel kb), zero pad cols 48..63
  u16* psw = &Ps[wave][0];
#pragma unroll
  for (int t = 0; t < 3; t++)
#pragma unroll
    for (int r = 0; r < 4; r++)
      psw[(quad * 4 + r) * PSS + t * 16 + r16] = f2bf(pr[t][r]);
#pragma unroll
  for (int r = 0; r < 4; r++)
    psw[(quad * 4 + r) * PSS + 48 + r16] = 0;

  // P A-frags (keys 0..31, 32..47+pad)
  bf16x8 pa0 = *(const bf16x8*)&psw[r16 * PSS + quad * 8];
  bf16x8 pa1 = *(const bf16x8*)&psw[r16 * PSS + 32 + quad * 8];

  // PV: 4 d-col tiles x 2 k-frags; V B-frags direct from transposed global
  const int kq1 = kb + quad * 8;
  const int kq2 = kb + 32 + quad * 8;
  const int o1 = (kq1 >> 4) * 1024 + (kq1 & 15);
  const int o2 = (kq2 >> 4) * 1024 + (kq2 & 15);
  f32x4 o[4];
#pragma unroll
  for (int c = 0; c < 4; c++) {
    const u16* vb = Vh + (16 * c + r16) * 16;
    bf16x8 v1 = *(const bf16x8*)(vb + o1);
    bf16x8 v2 = *(const bf16x8*)(vb + o2);
    f32x4 a = {};
    a = __builtin_amdgcn_mfma_f32_16x16x32_bf16(pa0, v1, a, 0, 0, 0);
    a = __builtin_amdgcn_mfma_f32_16x16x32_bf16(pa1, v2, a, 0, 0, 0);
    o[c] = a;
  }

  // O: stage through Ps (wave-private, P-frags already consumed), then
  // coalesced row stores: lane l handles rows l>>3 and 8+(l>>3), 16B each.
#pragma unroll
  for (int c = 0; c < 4; c++)
#pragma unroll
    for (int r = 0; r < 4; r++)
      psw[(quad * 4 + r) * PSS + 16 * c + r16] = f2bf(o[c][r]);
  {
    int rr = lane >> 3, cc = (lane & 7) * 8;
    u16x8 v0 = *(const u16x8*)&psw[rr * PSS + cc];
    u16x8 v1 = *(const u16x8*)&psw[(8 + rr) * PSS + cc];
    u16* ob = attn + (rowbase + qbase) * DMODEL + hc;
    *(u16x8*)(ob + (size_t)rr * DMODEL + cc) = v0;
    *(u16x8*)(ob + (size_t)(8 + rr) * DMODEL + cc) = v1;
  }
}

// ---------------- launch ----------------
extern "C" void kernel_launch(void* const* d_in, const int* in_sizes, int n_in,
                              void* d_out, int out_size, void* d_ws, size_t ws_size,
                              hipStream_t stream) {
  const float* x  = (const float*)d_in[0];
  const float* Wq = (const float*)d_in[1];
  const float* bq = (const float*)d_in[2];
  const float* Wk = (const float*)d_in[3];
  const float* bk = (const float*)d_in[4];
  const float* Wv = (const float*)d_in[5];
  const float* bv = (const float*)d_in[6];
  const float* Wo = (const float*)d_in[7];
  const float* bo = (const float*)d_in[8];
  float* out = (float*)d_out;
  char* ws = (char*)d_ws;

  u16* xb   = (u16*)(ws);                 // 8192*768 bf16
  u16* wqkv = (u16*)(ws + 12582912);      // 2304*768 bf16 (Wq,Wk,Wv rows)
  u16* wo_b = (u16*)(ws + 16121856);      // 768*768 bf16
  u16* qkv  = (u16*)(ws + 17301504);      // 3*6291456 bf16 (Q,K row-major; V transposed)
  u16* attnb = (u16*)(ws + 55050240);     // 8192*768 bf16

  cvt_all<<<8448, 256, 0, stream>>>(x, Wq, Wk, Wv, Wo, xb, wqkv, wo_b);

  // Q,K projection (row-major epilogue). grid 64x12 -> 768, XCD-swizzled
  gemm_bt<0, 4, 64><<<768, 256, 0, stream>>>(xb, wqkv, bq, bk, (void*)qkv);
  // V projection (block-transposed epilogue). grid 64x6 -> 384
  gemm_bt<2, 4, 64><<<384, 256, 0, stream>>>(xb, wqkv + 1179648, bv, bv,
                                             (void*)(qkv + 2 * QKV_STRIDE));
  attn_mfma<<<dim3(64, 12, 2), 256, 0, stream>>>(qkv, qkv + 2 * QKV_STRIDE, attnb);
  // out projection. grid 128x6 -> 768
  gemm_bt<1, 2, 128><<<768, 256, 0, stream>>>(attnb, wo_b, bo, bo, (void*)out);
}